// Round 2
// baseline (123.055 us; speedup 1.0000x reference)
//
#include <hip/hip_runtime.h>
#include <math.h>

#define H2 512
#define NB 64
#define TK 2048

#define LOG2E 1.44269504088896f
#define TWO_LOG2E 2.88539008177793f

// ---------------- K1: dec_fea = s_t_hat @ W_dp^T + b_dp  [NB, H2] ----------------
__global__ __launch_bounds__(256) void k_decproj(const float* __restrict__ s,
                                                 const float* __restrict__ W,
                                                 const float* __restrict__ bias,
                                                 float* __restrict__ dec) {
    const int bb = blockIdx.x;
    const int wave = threadIdx.x >> 6;
    const int lane = threadIdx.x & 63;
    const float* srow = s + bb * H2;
    float4 s0 = *(const float4*)(srow + lane * 8);
    float4 s1 = *(const float4*)(srow + lane * 8 + 4);
    #pragma unroll
    for (int i = 0; i < 8; ++i) {
        const int n = blockIdx.y * 32 + wave * 8 + i;
        const float* wrow = W + (size_t)n * H2;
        float4 w0 = *(const float4*)(wrow + lane * 8);
        float4 w1 = *(const float4*)(wrow + lane * 8 + 4);
        float acc = s0.x * w0.x + s0.y * w0.y + s0.z * w0.z + s0.w * w0.w +
                    s1.x * w1.x + s1.y * w1.y + s1.z * w1.z + s1.w * w1.w;
        #pragma unroll
        for (int off = 1; off < 64; off <<= 1) acc += __shfl_xor(acc, off, 64);
        if (lane == 0) dec[bb * H2 + n] = acc + bias[n];
    }
}

// ---------------- K2 fused: scores -> e = exp(score)*mask -> partial c_t ----------
// grid (TK/TILE, NB), block 256.
// Phase A: per wave, rows r = wave + 4*j; batches of 4 rows with 8 float4 loads upfront.
//   tanh(x) = 1 - 2*rcp(exp2(2*log2e*x)+1);  sum vw*tanh = sum(vw) + sum((-2vw)*rcp(...))
// Phase B: partial ct[sp] = sum_{t in tile} e_t * eo[t,:]  (128 float4 lanes x 2 t-halves)
template <int TILE>
__global__ __launch_bounds__(256) void k_fused(const float* __restrict__ ef,
                                               const float* __restrict__ eo,
                                               const float* __restrict__ dec,
                                               const float* __restrict__ cov,
                                               const float* __restrict__ mask,
                                               const float* __restrict__ wc,
                                               const float* __restrict__ vw,
                                               const float* __restrict__ vbp,
                                               float* __restrict__ w,
                                               float* __restrict__ part) {
    const int bb = blockIdx.y;
    const int sp = blockIdx.x;
    const int t0 = sp * TILE;
    const int tid = threadIdx.x;
    const int wave = tid >> 6, lane = tid & 63;
    const int n0 = lane * 8;

    __shared__ float e_lds[TILE];
    __shared__ float4 red[128];

    float4 d0 = *(const float4*)(dec + bb * H2 + n0);
    float4 d1 = *(const float4*)(dec + bb * H2 + n0 + 4);
    float4 c0 = *(const float4*)(wc + n0);
    float4 c1 = *(const float4*)(wc + n0 + 4);
    float4 v0 = *(const float4*)(vw + n0);
    float4 v1 = *(const float4*)(vw + n0 + 4);

    float vwsum = v0.x + v0.y + v0.z + v0.w + v1.x + v1.y + v1.z + v1.w;
    #pragma unroll
    for (int off = 1; off < 64; off <<= 1) vwsum += __shfl_xor(vwsum, off, 64);

    // prescale: arg = fma(E, 2L, fma(cov, wc*2L, dec*2L)); term = (-2vw)*rcp(exp2(arg)+1)
    d0.x *= TWO_LOG2E; d0.y *= TWO_LOG2E; d0.z *= TWO_LOG2E; d0.w *= TWO_LOG2E;
    d1.x *= TWO_LOG2E; d1.y *= TWO_LOG2E; d1.z *= TWO_LOG2E; d1.w *= TWO_LOG2E;
    c0.x *= TWO_LOG2E; c0.y *= TWO_LOG2E; c0.z *= TWO_LOG2E; c0.w *= TWO_LOG2E;
    c1.x *= TWO_LOG2E; c1.y *= TWO_LOG2E; c1.z *= TWO_LOG2E; c1.w *= TWO_LOG2E;
    v0.x *= -2.f; v0.y *= -2.f; v0.z *= -2.f; v0.w *= -2.f;
    v1.x *= -2.f; v1.y *= -2.f; v1.z *= -2.f; v1.w *= -2.f;
    const float vb = vbp[0];

    constexpr int R = TILE / 4;  // rows per wave
    #pragma unroll
    for (int j0 = 0; j0 < R; j0 += 4) {
        float4 ea[4][2];
        float cv4[4], mk4[4];
        #pragma unroll
        for (int i = 0; i < 4; ++i) {
            const int t = t0 + wave + 4 * (j0 + i);
            const float* p = ef + ((size_t)bb * TK + t) * H2 + n0;
            ea[i][0] = *(const float4*)p;
            ea[i][1] = *(const float4*)(p + 4);
            cv4[i] = cov[bb * TK + t];
            mk4[i] = mask[bb * TK + t];
        }
        #pragma unroll
        for (int i = 0; i < 4; ++i) {
            const float cv = cv4[i];
            #define TERM(E, D, C, V) \
                ((V) * __builtin_amdgcn_rcpf(__builtin_amdgcn_exp2f(fmaf((E), TWO_LOG2E, fmaf(cv, (C), (D)))) + 1.0f))
            float acc = TERM(ea[i][0].x, d0.x, c0.x, v0.x) + TERM(ea[i][0].y, d0.y, c0.y, v0.y) +
                        TERM(ea[i][0].z, d0.z, c0.z, v0.z) + TERM(ea[i][0].w, d0.w, c0.w, v0.w) +
                        TERM(ea[i][1].x, d1.x, c1.x, v1.x) + TERM(ea[i][1].y, d1.y, c1.y, v1.y) +
                        TERM(ea[i][1].z, d1.z, c1.z, v1.z) + TERM(ea[i][1].w, d1.w, c1.w, v1.w);
            #undef TERM
            #pragma unroll
            for (int off = 1; off < 64; off <<= 1) acc += __shfl_xor(acc, off, 64);
            if (lane == 0) {
                const int r = wave + 4 * (j0 + i);
                const float score = vwsum + acc + vb;
                const float e = __builtin_amdgcn_exp2f(score * LOG2E) * mk4[i];
                e_lds[r] = e;
                w[bb * TK + t0 + r] = e;
            }
        }
    }
    __syncthreads();

    // Phase B
    const int ng = tid & 127, th = tid >> 7;
    float4 acc = make_float4(0.f, 0.f, 0.f, 0.f);
    #pragma unroll 8
    for (int i = 0; i < TILE / 2; ++i) {
        const int r = th + 2 * i;
        const float a = e_lds[r];
        const float4 vv = *((const float4*)(eo + ((size_t)bb * TK + t0 + r) * H2) + ng);
        acc.x = fmaf(a, vv.x, acc.x);
        acc.y = fmaf(a, vv.y, acc.y);
        acc.z = fmaf(a, vv.z, acc.z);
        acc.w = fmaf(a, vv.w, acc.w);
    }
    if (th) red[ng] = acc;
    __syncthreads();
    if (!th) {
        const float4 o = red[ng];
        acc.x += o.x; acc.y += o.y; acc.z += o.z; acc.w += o.w;
        *(float4*)(part + ((size_t)bb * (TK / TILE) + sp) * H2 + ng * 4) = acc;
    }
}

// ---------------- K3a: row sum -> attn = w/sum, covnew = cov + attn, invs[b] ------
__global__ __launch_bounds__(256) void k_finA(const float* __restrict__ w,
                                              const float* __restrict__ cov,
                                              float* __restrict__ attn,
                                              float* __restrict__ covnew,
                                              float* __restrict__ invs) {
    const int bb = blockIdx.x;
    const int tid = threadIdx.x;
    const int lane = tid & 63, wave = tid >> 6;
    float v[8];
    float sum = 0.f;
    #pragma unroll
    for (int i = 0; i < 8; ++i) {
        v[i] = w[bb * TK + tid + 256 * i];
        sum += v[i];
    }
    #pragma unroll
    for (int off = 1; off < 64; off <<= 1) sum += __shfl_xor(sum, off, 64);
    __shared__ float reds[4];
    if (lane == 0) reds[wave] = sum;
    __syncthreads();
    sum = reds[0] + reds[1] + reds[2] + reds[3];
    const float inv = 1.0f / sum;
    #pragma unroll
    for (int i = 0; i < 8; ++i) {
        const int t = tid + 256 * i;
        const float a = v[i] * inv;
        attn[bb * TK + t] = a;
        covnew[bb * TK + t] = cov[bb * TK + t] + a;
    }
    if (tid == 0) invs[bb] = inv;
}

// ---------------- K3b: ct[b] = inv[b] * sum_sp part[b,sp,:] -----------------------
template <int SPLIT>
__global__ __launch_bounds__(128) void k_finB(const float* __restrict__ part,
                                              const float* __restrict__ invs,
                                              float* __restrict__ ct) {
    const int bb = blockIdx.x;
    const int tid = threadIdx.x;
    float4 acc = make_float4(0.f, 0.f, 0.f, 0.f);
    #pragma unroll 8
    for (int sp = 0; sp < SPLIT; ++sp) {
        const float4 p = *((const float4*)(part + ((size_t)bb * SPLIT + sp) * H2) + tid);
        acc.x += p.x; acc.y += p.y; acc.z += p.z; acc.w += p.w;
    }
    const float inv = invs[bb];
    float4 o;
    o.x = acc.x * inv; o.y = acc.y * inv; o.z = acc.z * inv; o.w = acc.w * inv;
    *(float4*)(ct + bb * H2 + tid * 4) = o;
}

extern "C" void kernel_launch(void* const* d_in, const int* in_sizes, int n_in,
                              void* d_out, int out_size, void* d_ws, size_t ws_size,
                              hipStream_t stream) {
    const float* s_t_hat  = (const float*)d_in[0];
    const float* enc_out  = (const float*)d_in[1];
    const float* enc_feat = (const float*)d_in[2];
    const float* mask     = (const float*)d_in[3];
    const float* cov      = (const float*)d_in[4];
    const float* W_dp     = (const float*)d_in[5];
    const float* b_dp     = (const float*)d_in[6];
    const float* W_c      = (const float*)d_in[7];
    const float* v_w      = (const float*)d_in[8];
    const float* v_b      = (const float*)d_in[9];

    float* out = (float*)d_out;
    float* ct     = out;                 // [NB, H2]
    float* attn   = out + NB * H2;       // [NB, TK]
    float* covnew = attn + NB * TK;      // [NB, TK]

    float* dec  = (float*)d_ws;          // [NB, H2]
    float* w    = dec + NB * H2;         // [NB, TK]  unnormalized e*mask
    float* invs = w + NB * TK;           // [NB] (+pad)
    float* part = invs + 256;            // [NB, SPLIT, H2]

    const size_t base_floats = (size_t)NB * H2 + (size_t)NB * TK + 256;
    auto need = [&](int tile) {
        return (base_floats + (size_t)NB * (TK / tile) * H2) * sizeof(float);
    };

    k_decproj<<<dim3(NB, 16), 256, 0, stream>>>(s_t_hat, W_dp, b_dp, dec);

    if (ws_size >= need(32)) {
        k_fused<32><<<dim3(TK / 32, NB), 256, 0, stream>>>(enc_feat, enc_out, dec, cov, mask,
                                                           W_c, v_w, v_b, w, part);
        k_finA<<<NB, 256, 0, stream>>>(w, cov, attn, covnew, invs);
        k_finB<TK / 32><<<NB, 128, 0, stream>>>(part, invs, ct);
    } else if (ws_size >= need(64)) {
        k_fused<64><<<dim3(TK / 64, NB), 256, 0, stream>>>(enc_feat, enc_out, dec, cov, mask,
                                                           W_c, v_w, v_b, w, part);
        k_finA<<<NB, 256, 0, stream>>>(w, cov, attn, covnew, invs);
        k_finB<TK / 64><<<NB, 128, 0, stream>>>(part, invs, ct);
    } else {
        k_fused<128><<<dim3(TK / 128, NB), 256, 0, stream>>>(enc_feat, enc_out, dec, cov, mask,
                                                             W_c, v_w, v_b, w, part);
        k_finA<<<NB, 256, 0, stream>>>(w, cov, attn, covnew, invs);
        k_finB<TK / 128><<<NB, 128, 0, stream>>>(part, invs, ct);
    }
}

// Round 3
// 118.568 us; speedup vs baseline: 1.0378x; 1.0378x over previous
//
#include <hip/hip_runtime.h>
#include <math.h>

#define H2 512
#define NB 64
#define TK 2048
#define SPLIT 16
#define TROWS 128

#define LOG2E 1.44269504088896f
#define TWO_LOG2E 2.88539008177793f

// ---------------- K1: dec_fea = s_t_hat @ W_dp^T + b_dp  [NB, H2] ----------------
__global__ __launch_bounds__(256) void k_decproj(const float* __restrict__ s,
                                                 const float* __restrict__ W,
                                                 const float* __restrict__ bias,
                                                 float* __restrict__ dec) {
    const int bb = blockIdx.x;
    const int wave = threadIdx.x >> 6;
    const int lane = threadIdx.x & 63;
    const float* srow = s + bb * H2;
    float4 s0 = *(const float4*)(srow + lane * 8);
    float4 s1 = *(const float4*)(srow + lane * 8 + 4);
    #pragma unroll
    for (int i = 0; i < 8; ++i) {
        const int n = blockIdx.y * 32 + wave * 8 + i;
        const float* wrow = W + (size_t)n * H2;
        float4 w0 = *(const float4*)(wrow + lane * 8);
        float4 w1 = *(const float4*)(wrow + lane * 8 + 4);
        float acc = s0.x * w0.x + s0.y * w0.y + s0.z * w0.z + s0.w * w0.w +
                    s1.x * w1.x + s1.y * w1.y + s1.z * w1.z + s1.w * w1.w;
        #pragma unroll
        for (int off = 1; off < 64; off <<= 1) acc += __shfl_xor(acc, off, 64);
        if (lane == 0) dec[bb * H2 + n] = acc + bias[n];
    }
}

// ---------------- K2: e[b,t] = exp(score)*mask, score via LDS bulk reduce ---------
// grid (TK/TROWS, NB), block 512 (8 waves, 16 rows each, batches of 8).
// Streaming path has NO cross-lane ops: lane partials -> LDS, one barrier, bulk reduce.
__global__ __launch_bounds__(512) void k_scores2(const float* __restrict__ ef,
                                                 const float* __restrict__ cov,
                                                 const float* __restrict__ mask,
                                                 const float* __restrict__ dec,
                                                 const float* __restrict__ wc,
                                                 const float* __restrict__ vw,
                                                 const float* __restrict__ vbp,
                                                 float* __restrict__ w) {
    const int bb = blockIdx.y;
    const int t0 = blockIdx.x * TROWS;
    const int tid = threadIdx.x;
    const int wave = tid >> 6, lane = tid & 63;
    const int n0 = lane * 8;

    __shared__ float pl[TROWS][68];  // [row][lane] partials; pad 68 for reduce reads

    float4 d0 = *(const float4*)(dec + bb * H2 + n0);
    float4 d1 = *(const float4*)(dec + bb * H2 + n0 + 4);
    float4 c0 = *(const float4*)(wc + n0);
    float4 c1 = *(const float4*)(wc + n0 + 4);
    float4 v0 = *(const float4*)(vw + n0);
    float4 v1 = *(const float4*)(vw + n0 + 4);

    float vwsum = v0.x + v0.y + v0.z + v0.w + v1.x + v1.y + v1.z + v1.w;
    #pragma unroll
    for (int off = 1; off < 64; off <<= 1) vwsum += __shfl_xor(vwsum, off, 64);

    // prescale so inner arg = fma(E, 2L, fma(cov, wc*2L, dec*2L)); term = (-2vw)*rcp(exp2(arg)+1)
    d0.x *= TWO_LOG2E; d0.y *= TWO_LOG2E; d0.z *= TWO_LOG2E; d0.w *= TWO_LOG2E;
    d1.x *= TWO_LOG2E; d1.y *= TWO_LOG2E; d1.z *= TWO_LOG2E; d1.w *= TWO_LOG2E;
    c0.x *= TWO_LOG2E; c0.y *= TWO_LOG2E; c0.z *= TWO_LOG2E; c0.w *= TWO_LOG2E;
    c1.x *= TWO_LOG2E; c1.y *= TWO_LOG2E; c1.z *= TWO_LOG2E; c1.w *= TWO_LOG2E;
    v0.x *= -2.f; v0.y *= -2.f; v0.z *= -2.f; v0.w *= -2.f;
    v1.x *= -2.f; v1.y *= -2.f; v1.z *= -2.f; v1.w *= -2.f;
    const float vb = vbp[0];

    #pragma unroll
    for (int j0 = 0; j0 < 16; j0 += 8) {
        float4 ea[8][2];
        float cv8[8];
        #pragma unroll
        for (int i = 0; i < 8; ++i) {
            const int r = wave * 16 + j0 + i;
            const float* p = ef + ((size_t)bb * TK + t0 + r) * H2 + n0;
            ea[i][0] = *(const float4*)p;
            ea[i][1] = *(const float4*)(p + 4);
            cv8[i] = cov[bb * TK + t0 + r];
        }
        #pragma unroll
        for (int i = 0; i < 8; ++i) {
            const float cv = cv8[i];
            #define TERM(E, D, C, V) \
                ((V) * __builtin_amdgcn_rcpf(__builtin_amdgcn_exp2f(fmaf((E), TWO_LOG2E, fmaf(cv, (C), (D)))) + 1.0f))
            const float acc = TERM(ea[i][0].x, d0.x, c0.x, v0.x) + TERM(ea[i][0].y, d0.y, c0.y, v0.y) +
                              TERM(ea[i][0].z, d0.z, c0.z, v0.z) + TERM(ea[i][0].w, d0.w, c0.w, v0.w) +
                              TERM(ea[i][1].x, d1.x, c1.x, v1.x) + TERM(ea[i][1].y, d1.y, c1.y, v1.y) +
                              TERM(ea[i][1].z, d1.z, c1.z, v1.z) + TERM(ea[i][1].w, d1.w, c1.w, v1.w);
            #undef TERM
            pl[wave * 16 + j0 + i][lane] = acc;
        }
    }
    __syncthreads();

    // bulk reduce: 4 threads per row, 16 floats each, 2 shfl steps
    const int r = tid >> 2, q = tid & 3;
    const float* prow = &pl[r][q * 16];
    const float4 x0 = *(const float4*)(prow);
    const float4 x1 = *(const float4*)(prow + 4);
    const float4 x2 = *(const float4*)(prow + 8);
    const float4 x3 = *(const float4*)(prow + 12);
    float s = x0.x + x0.y + x0.z + x0.w + x1.x + x1.y + x1.z + x1.w +
              x2.x + x2.y + x2.z + x2.w + x3.x + x3.y + x3.z + x3.w;
    s += __shfl_xor(s, 1, 64);
    s += __shfl_xor(s, 2, 64);
    if (q == 0) {
        const int t = t0 + r;
        const float score = vwsum + s + vb;
        w[bb * TK + t] = __builtin_amdgcn_exp2f(score * LOG2E) * mask[bb * TK + t];
    }
}

// ---------------- K4: part[b,sp,:] = sum_{t in sp} e_t * eo[t,:] ------------------
// grid (SPLIT, NB), block 256: 128 float4-columns x 2 contiguous row-halves.
__global__ __launch_bounds__(256) void k_ctpart(const float* __restrict__ eo,
                                                const float* __restrict__ w,
                                                float* __restrict__ part) {
    const int bb = blockIdx.y, sp = blockIdx.x;
    const int tid = threadIdx.x;
    const int ng = tid & 127, th = tid >> 7;
    const int t0 = sp * (TK / SPLIT) + th * 64;
    const float* wp = w + bb * TK + t0;
    const float4* ep = (const float4*)(eo + ((size_t)bb * TK + t0) * H2) + ng;

    float4 acc = make_float4(0.f, 0.f, 0.f, 0.f);
    #pragma unroll 2
    for (int i0 = 0; i0 < 64; i0 += 4) {
        const float4 a4 = *(const float4*)(wp + i0);
        const float4 r0 = ep[(size_t)(i0 + 0) * 128];
        const float4 r1 = ep[(size_t)(i0 + 1) * 128];
        const float4 r2 = ep[(size_t)(i0 + 2) * 128];
        const float4 r3 = ep[(size_t)(i0 + 3) * 128];
        acc.x = fmaf(a4.x, r0.x, acc.x); acc.y = fmaf(a4.x, r0.y, acc.y);
        acc.z = fmaf(a4.x, r0.z, acc.z); acc.w = fmaf(a4.x, r0.w, acc.w);
        acc.x = fmaf(a4.y, r1.x, acc.x); acc.y = fmaf(a4.y, r1.y, acc.y);
        acc.z = fmaf(a4.y, r1.z, acc.z); acc.w = fmaf(a4.y, r1.w, acc.w);
        acc.x = fmaf(a4.z, r2.x, acc.x); acc.y = fmaf(a4.z, r2.y, acc.y);
        acc.z = fmaf(a4.z, r2.z, acc.z); acc.w = fmaf(a4.z, r2.w, acc.w);
        acc.x = fmaf(a4.w, r3.x, acc.x); acc.y = fmaf(a4.w, r3.y, acc.y);
        acc.z = fmaf(a4.w, r3.z, acc.z); acc.w = fmaf(a4.w, r3.w, acc.w);
    }
    __shared__ float4 red[128];
    if (th) red[ng] = acc;
    __syncthreads();
    if (!th) {
        const float4 o = red[ng];
        acc.x += o.x; acc.y += o.y; acc.z += o.z; acc.w += o.w;
        *(float4*)(part + ((size_t)bb * SPLIT + sp) * H2 + ng * 4) = acc;
    }
}

// ---------------- K3: finalize — sum, attn, covnew, ct (one kernel) ---------------
__global__ __launch_bounds__(512) void k_finish(const float* __restrict__ w,
                                                const float* __restrict__ cov,
                                                const float* __restrict__ part,
                                                float* __restrict__ attn,
                                                float* __restrict__ covnew,
                                                float* __restrict__ ct) {
    const int bb = blockIdx.x;
    const int tid = threadIdx.x;
    const int lane = tid & 63, wave = tid >> 6;

    const float4 w4 = *(const float4*)(w + bb * TK + tid * 4);
    float s = w4.x + w4.y + w4.z + w4.w;
    #pragma unroll
    for (int off = 1; off < 64; off <<= 1) s += __shfl_xor(s, off, 64);
    __shared__ float rs[8];
    if (lane == 0) rs[wave] = s;
    __syncthreads();
    s = rs[0] + rs[1] + rs[2] + rs[3] + rs[4] + rs[5] + rs[6] + rs[7];
    const float inv = 1.0f / s;

    const float4 c4 = *(const float4*)(cov + bb * TK + tid * 4);
    float4 a4, n4;
    a4.x = w4.x * inv; a4.y = w4.y * inv; a4.z = w4.z * inv; a4.w = w4.w * inv;
    n4.x = c4.x + a4.x; n4.y = c4.y + a4.y; n4.z = c4.z + a4.z; n4.w = c4.w + a4.w;
    *(float4*)(attn + bb * TK + tid * 4) = a4;
    *(float4*)(covnew + bb * TK + tid * 4) = n4;

    float acc = 0.f;
    #pragma unroll
    for (int sp = 0; sp < SPLIT; ++sp) acc += part[((size_t)bb * SPLIT + sp) * H2 + tid];
    ct[bb * H2 + tid] = acc * inv;
}

extern "C" void kernel_launch(void* const* d_in, const int* in_sizes, int n_in,
                              void* d_out, int out_size, void* d_ws, size_t ws_size,
                              hipStream_t stream) {
    const float* s_t_hat  = (const float*)d_in[0];
    const float* enc_out  = (const float*)d_in[1];
    const float* enc_feat = (const float*)d_in[2];
    const float* mask     = (const float*)d_in[3];
    const float* cov      = (const float*)d_in[4];
    const float* W_dp     = (const float*)d_in[5];
    const float* b_dp     = (const float*)d_in[6];
    const float* W_c      = (const float*)d_in[7];
    const float* v_w      = (const float*)d_in[8];
    const float* v_b      = (const float*)d_in[9];

    float* out = (float*)d_out;
    float* ct     = out;                 // [NB, H2]
    float* attn   = out + NB * H2;       // [NB, TK]
    float* covnew = attn + NB * TK;      // [NB, TK]

    float* dec  = (float*)d_ws;          // [NB, H2]           128 KB
    float* w    = dec + NB * H2;         // [NB, TK]           512 KB (unnormalized e*mask)
    float* part = w + NB * TK;           // [NB, SPLIT, H2]    2 MB   (ws >= 8.9 MB verified in R2)

    k_decproj<<<dim3(NB, 16), 256, 0, stream>>>(s_t_hat, W_dp, b_dp, dec);
    k_scores2<<<dim3(TK / TROWS, NB), 512, 0, stream>>>(enc_feat, cov, mask, dec, W_c, v_w, v_b, w);
    k_ctpart<<<dim3(SPLIT, NB), 256, 0, stream>>>(enc_out, w, part);
    k_finish<<<NB, 512, 0, stream>>>(w, cov, part, attn, covnew, ct);
}

// Round 4
// 113.633 us; speedup vs baseline: 1.0829x; 1.0434x over previous
//
#include <hip/hip_runtime.h>
#include <math.h>

#define H2 512
#define NB 64
#define TK 2048
#define SPLIT 16

#define LOG2E 1.44269504088896f
#define TWO_LOG2E 2.88539008177793f

// ---------------- K1: dec_fea = s_t_hat @ W_dp^T + b_dp  [NB, H2] ----------------
__global__ __launch_bounds__(256) void k_decproj(const float* __restrict__ s,
                                                 const float* __restrict__ W,
                                                 const float* __restrict__ bias,
                                                 float* __restrict__ dec) {
    const int bb = blockIdx.x;
    const int wave = threadIdx.x >> 6;
    const int lane = threadIdx.x & 63;
    const float* srow = s + bb * H2;
    float4 s0 = *(const float4*)(srow + lane * 8);
    float4 s1 = *(const float4*)(srow + lane * 8 + 4);
    #pragma unroll
    for (int i = 0; i < 8; ++i) {
        const int n = blockIdx.y * 32 + wave * 8 + i;
        const float* wrow = W + (size_t)n * H2;
        float4 w0 = *(const float4*)(wrow + lane * 8);
        float4 w1 = *(const float4*)(wrow + lane * 8 + 4);
        float acc = s0.x * w0.x + s0.y * w0.y + s0.z * w0.z + s0.w * w0.w +
                    s1.x * w1.x + s1.y * w1.y + s1.z * w1.z + s1.w * w1.w;
        #pragma unroll
        for (int off = 1; off < 64; off <<= 1) acc += __shfl_xor(acc, off, 64);
        if (lane == 0) dec[bb * H2 + n] = acc + bias[n];
    }
}

// ---------------- K2: e[b,t]=exp(score)*mask. 64 rows/block, 2-deep pipelined -----
// grid (TK/64, NB), block 256 (4 waves x 16 rows, batches of 4 rows, dbuf'd loads).
// REP: idempotent internal repeat (diagnostic; REP=1 for production).
template <int REP>
__global__ __launch_bounds__(256) void k_scores2(const float* __restrict__ ef,
                                                 const float* __restrict__ cov,
                                                 const float* __restrict__ mask,
                                                 const float* __restrict__ dec,
                                                 const float* __restrict__ wc,
                                                 const float* __restrict__ vw,
                                                 const float* __restrict__ vbp,
                                                 float* __restrict__ w) {
    const int bb = blockIdx.y;
    const int t0 = blockIdx.x * 64;
    const int tid = threadIdx.x;
    const int wave = tid >> 6, lane = tid & 63;
    const int n0 = lane * 8;

    __shared__ float pl[64][68];

    float4 d0 = *(const float4*)(dec + bb * H2 + n0);
    float4 d1 = *(const float4*)(dec + bb * H2 + n0 + 4);
    float4 c0 = *(const float4*)(wc + n0);
    float4 c1 = *(const float4*)(wc + n0 + 4);
    float4 v0 = *(const float4*)(vw + n0);
    float4 v1 = *(const float4*)(vw + n0 + 4);

    float vwsum = v0.x + v0.y + v0.z + v0.w + v1.x + v1.y + v1.z + v1.w;
    #pragma unroll
    for (int off = 1; off < 64; off <<= 1) vwsum += __shfl_xor(vwsum, off, 64);

    d0.x *= TWO_LOG2E; d0.y *= TWO_LOG2E; d0.z *= TWO_LOG2E; d0.w *= TWO_LOG2E;
    d1.x *= TWO_LOG2E; d1.y *= TWO_LOG2E; d1.z *= TWO_LOG2E; d1.w *= TWO_LOG2E;
    c0.x *= TWO_LOG2E; c0.y *= TWO_LOG2E; c0.z *= TWO_LOG2E; c0.w *= TWO_LOG2E;
    c1.x *= TWO_LOG2E; c1.y *= TWO_LOG2E; c1.z *= TWO_LOG2E; c1.w *= TWO_LOG2E;
    v0.x *= -2.f; v0.y *= -2.f; v0.z *= -2.f; v0.w *= -2.f;
    v1.x *= -2.f; v1.y *= -2.f; v1.z *= -2.f; v1.w *= -2.f;
    const float vb = vbp[0];

    const size_t rowbase = (size_t)bb * TK + t0;

    #pragma unroll 1
    for (int rep = 0; rep < REP; ++rep) {
        float4 ea[2][4][2];
        float cv[2][4];
        #pragma unroll
        for (int i = 0; i < 4; ++i) {
            const int r = wave + 4 * i;
            const float* p = ef + (rowbase + r) * H2 + n0;
            ea[0][i][0] = *(const float4*)p;
            ea[0][i][1] = *(const float4*)(p + 4);
            cv[0][i] = cov[rowbase + r];
        }
        #pragma unroll
        for (int j0 = 0; j0 < 16; j0 += 4) {
            const int cur = (j0 >> 2) & 1;
            const int nxt = cur ^ 1;
            if (j0 + 4 < 16) {
                #pragma unroll
                for (int i = 0; i < 4; ++i) {
                    const int r = wave + 4 * (j0 + 4 + i);
                    const float* p = ef + (rowbase + r) * H2 + n0;
                    ea[nxt][i][0] = *(const float4*)p;
                    ea[nxt][i][1] = *(const float4*)(p + 4);
                    cv[nxt][i] = cov[rowbase + r];
                }
            }
            #pragma unroll
            for (int i = 0; i < 4; ++i) {
                const float cvv = cv[cur][i];
                #define TERM(E, D, C, V) \
                    ((V) * __builtin_amdgcn_rcpf(__builtin_amdgcn_exp2f(fmaf((E), TWO_LOG2E, fmaf(cvv, (C), (D)))) + 1.0f))
                const float acc =
                    TERM(ea[cur][i][0].x, d0.x, c0.x, v0.x) + TERM(ea[cur][i][0].y, d0.y, c0.y, v0.y) +
                    TERM(ea[cur][i][0].z, d0.z, c0.z, v0.z) + TERM(ea[cur][i][0].w, d0.w, c0.w, v0.w) +
                    TERM(ea[cur][i][1].x, d1.x, c1.x, v1.x) + TERM(ea[cur][i][1].y, d1.y, c1.y, v1.y) +
                    TERM(ea[cur][i][1].z, d1.z, c1.z, v1.z) + TERM(ea[cur][i][1].w, d1.w, c1.w, v1.w);
                #undef TERM
                pl[wave + 4 * (j0 + i)][lane] = acc;
            }
        }
        __syncthreads();

        // bulk reduce: 4 threads/row, 16 floats each, 2 shfl steps
        const int r = tid >> 2, q = tid & 3;
        const float* prow = &pl[r][q * 16];
        const float4 x0 = *(const float4*)(prow);
        const float4 x1 = *(const float4*)(prow + 4);
        const float4 x2 = *(const float4*)(prow + 8);
        const float4 x3 = *(const float4*)(prow + 12);
        float s = x0.x + x0.y + x0.z + x0.w + x1.x + x1.y + x1.z + x1.w +
                  x2.x + x2.y + x2.z + x2.w + x3.x + x3.y + x3.z + x3.w;
        s += __shfl_xor(s, 1, 64);
        s += __shfl_xor(s, 2, 64);
        if (q == 0) {
            const float score = vwsum + s + vb;
            w[rowbase + r] = __builtin_amdgcn_exp2f(score * LOG2E) * mask[rowbase + r];
        }
        __syncthreads();
    }
}

// ---------------- K4: part[b,sp,:] = sum_t e_t * eo[t,:], 2-deep pipelined --------
// grid (SPLIT, NB), block 256: 128 float4-cols x 2 halves of 64 contiguous rows.
template <int REP>
__global__ __launch_bounds__(256) void k_ctpart(const float* __restrict__ eo,
                                                const float* __restrict__ w,
                                                float* __restrict__ part) {
    const int bb = blockIdx.y, sp = blockIdx.x;
    const int tid = threadIdx.x;
    const int ng = tid & 127, th = tid >> 7;
    const int t0 = sp * 128 + th * 64;
    const float* wp = w + bb * TK + t0;
    const float4* ep = (const float4*)(eo + ((size_t)bb * TK + t0) * H2) + ng;
    __shared__ float4 red[128];

    #define FMA4(a, r) do { acc.x = fmaf((a), (r).x, acc.x); acc.y = fmaf((a), (r).y, acc.y); \
                            acc.z = fmaf((a), (r).z, acc.z); acc.w = fmaf((a), (r).w, acc.w); } while (0)

    #pragma unroll 1
    for (int rep = 0; rep < REP; ++rep) {
        float4 acc = make_float4(0.f, 0.f, 0.f, 0.f);
        float4 rr[2][8];
        float4 wv[2][2];
        #pragma unroll
        for (int i = 0; i < 8; ++i) rr[0][i] = ep[(size_t)i * 128];
        wv[0][0] = *(const float4*)(wp);
        wv[0][1] = *(const float4*)(wp + 4);

        #pragma unroll
        for (int c = 0; c < 8; ++c) {
            const int cur = c & 1, nxt = cur ^ 1;
            if (c < 7) {
                const int base = (c + 1) * 8;
                #pragma unroll
                for (int i = 0; i < 8; ++i) rr[nxt][i] = ep[(size_t)(base + i) * 128];
                wv[nxt][0] = *(const float4*)(wp + base);
                wv[nxt][1] = *(const float4*)(wp + base + 4);
            }
            FMA4(wv[cur][0].x, rr[cur][0]);
            FMA4(wv[cur][0].y, rr[cur][1]);
            FMA4(wv[cur][0].z, rr[cur][2]);
            FMA4(wv[cur][0].w, rr[cur][3]);
            FMA4(wv[cur][1].x, rr[cur][4]);
            FMA4(wv[cur][1].y, rr[cur][5]);
            FMA4(wv[cur][1].z, rr[cur][6]);
            FMA4(wv[cur][1].w, rr[cur][7]);
        }

        if (th) red[ng] = acc;
        __syncthreads();
        if (!th) {
            const float4 o = red[ng];
            acc.x += o.x; acc.y += o.y; acc.z += o.z; acc.w += o.w;
            *(float4*)(part + ((size_t)bb * SPLIT + sp) * H2 + ng * 4) = acc;
        }
        __syncthreads();
    }
    #undef FMA4
}

// ---------------- K3: finalize — sum, attn, covnew, ct (one kernel) ---------------
__global__ __launch_bounds__(512) void k_finish(const float* __restrict__ w,
                                                const float* __restrict__ cov,
                                                const float* __restrict__ part,
                                                float* __restrict__ attn,
                                                float* __restrict__ covnew,
                                                float* __restrict__ ct) {
    const int bb = blockIdx.x;
    const int tid = threadIdx.x;
    const int lane = tid & 63, wave = tid >> 6;

    const float4 w4 = *(const float4*)(w + bb * TK + tid * 4);
    float s = w4.x + w4.y + w4.z + w4.w;
    #pragma unroll
    for (int off = 1; off < 64; off <<= 1) s += __shfl_xor(s, off, 64);
    __shared__ float rs[8];
    if (lane == 0) rs[wave] = s;
    __syncthreads();
    s = rs[0] + rs[1] + rs[2] + rs[3] + rs[4] + rs[5] + rs[6] + rs[7];
    const float inv = 1.0f / s;

    const float4 c4 = *(const float4*)(cov + bb * TK + tid * 4);
    float4 a4, n4;
    a4.x = w4.x * inv; a4.y = w4.y * inv; a4.z = w4.z * inv; a4.w = w4.w * inv;
    n4.x = c4.x + a4.x; n4.y = c4.y + a4.y; n4.z = c4.z + a4.z; n4.w = c4.w + a4.w;
    *(float4*)(attn + bb * TK + tid * 4) = a4;
    *(float4*)(covnew + bb * TK + tid * 4) = n4;

    float acc = 0.f;
    #pragma unroll
    for (int sp = 0; sp < SPLIT; ++sp) acc += part[((size_t)bb * SPLIT + sp) * H2 + tid];
    ct[bb * H2 + tid] = acc * inv;
}

extern "C" void kernel_launch(void* const* d_in, const int* in_sizes, int n_in,
                              void* d_out, int out_size, void* d_ws, size_t ws_size,
                              hipStream_t stream) {
    const float* s_t_hat  = (const float*)d_in[0];
    const float* enc_out  = (const float*)d_in[1];
    const float* enc_feat = (const float*)d_in[2];
    const float* mask     = (const float*)d_in[3];
    const float* cov      = (const float*)d_in[4];
    const float* W_dp     = (const float*)d_in[5];
    const float* b_dp     = (const float*)d_in[6];
    const float* W_c      = (const float*)d_in[7];
    const float* v_w      = (const float*)d_in[8];
    const float* v_b      = (const float*)d_in[9];

    float* out = (float*)d_out;
    float* ct     = out;                 // [NB, H2]
    float* attn   = out + NB * H2;       // [NB, TK]
    float* covnew = attn + NB * TK;      // [NB, TK]

    float* dec  = (float*)d_ws;          // [NB, H2]
    float* w    = dec + NB * H2;         // [NB, TK]
    float* part = w + NB * TK;           // [NB, SPLIT, H2]

    k_decproj<<<dim3(NB, 16), 256, 0, stream>>>(s_t_hat, W_dp, b_dp, dec);
    // DIAGNOSTIC: REP=4 so these two surface in rocprof top-5 (idempotent).
    k_scores2<4><<<dim3(TK / 64, NB), 256, 0, stream>>>(enc_feat, cov, mask, dec, W_c, v_w, v_b, w);
    k_ctpart<4><<<dim3(SPLIT, NB), 256, 0, stream>>>(enc_out, w, part);
    k_finish<<<NB, 512, 0, stream>>>(w, cov, part, attn, covnew, ct);
}